// Round 7
// baseline (129.561 us; speedup 1.0000x reference)
//
#include <hip/hip_runtime.h>
#include <hip/hip_bf16.h>

#define IN_F   1024
#define OUT_F  64
#define INTER  32
#define BATCH  512
#define NCOL   2048              // OUT_F * INTER
#define OUT_W  1088              // IN_F + OUT_F

typedef short bf16x8 __attribute__((ext_vector_type(8)));  // 8 bf16 (4 VGPRs)
typedef float f32x4  __attribute__((ext_vector_type(4)));  // 4 fp32 acc

__device__ __forceinline__ unsigned short f2bf(float v) {
    __hip_bfloat16 h = __float2bfloat16(v);
    return *reinterpret_cast<unsigned short*>(&h);
}

// ---------------- Prep: copy x -> out (+zero feature cols), cast x -> xb, transpose T -> Bt ----
__global__ __launch_bounds__(256) void prep_kernel(const float* __restrict__ x,
                                                   const float* __restrict__ T,
                                                   float* __restrict__ out,
                                                   unsigned short* __restrict__ xb,
                                                   unsigned short* __restrict__ Bt) {
    const int tid = threadIdx.x;
    if (blockIdx.x < BATCH) {
        const int r = blockIdx.x;
        const float4 v = ((const float4*)(x + (size_t)r * IN_F))[tid];
        *(float4*)(out + (size_t)r * OUT_W + tid * 4) = v;
        unsigned short h[4] = {f2bf(v.x), f2bf(v.y), f2bf(v.z), f2bf(v.w)};
        *(uint2*)(xb + (size_t)r * IN_F + tid * 4) = *(uint2*)h;
        if (tid < OUT_F / 4)   // zero-init minibatch-feature cols (pairwise accumulates atomically)
            *(float4*)(out + (size_t)r * OUT_W + IN_F + tid * 4) = make_float4(0.f, 0.f, 0.f, 0.f);
    } else {
        __shared__ unsigned short ldsT[64][72];   // [n][k], row stride 144B (16B-aligned)
        const int bid = blockIdx.x - BATCH;
        const int n0 = (bid & 31) * 64;
        const int k0 = (bid >> 5) * 64;
        const int nl = tid & 63;
        const int kc = (tid >> 6) * 16;
        unsigned short u[16];
        #pragma unroll
        for (int j = 0; j < 16; ++j)
            u[j] = f2bf(T[(size_t)(k0 + kc + j) * NCOL + n0 + nl]);
        *(uint4*)&ldsT[nl][kc]     = *(uint4*)&u[0];
        *(uint4*)&ldsT[nl][kc + 8] = *(uint4*)&u[8];
        __syncthreads();
        const int n2  = tid >> 2;
        const int kc2 = (tid & 3) * 16;
        uint4 a = *(uint4*)&ldsT[n2][kc2];
        uint4 b = *(uint4*)&ldsT[n2][kc2 + 8];
        unsigned short* dst = Bt + (size_t)(n0 + n2) * IN_F + k0 + kc2;
        *(uint4*)dst       = a;
        *(uint4*)(dst + 8) = b;
    }
}

// ---------------- GEMM (bf16 MFMA, no LDS, no barriers) ----------------
__global__ __launch_bounds__(256) void gemm_kernel(const unsigned short* __restrict__ xb,
                                                   const unsigned short* __restrict__ Bt,
                                                   float* __restrict__ Mt) {
    const int tid  = threadIdx.x;
    const int wave = tid >> 6, lane = tid & 63;
    const int quad = lane >> 4, lr = lane & 15;
    const int m0 = (blockIdx.y * 4 + wave) * 16;
    const int n0 = blockIdx.x * 32;

    const unsigned short* pA  = xb + (size_t)(m0 + lr) * IN_F + quad * 8;
    const unsigned short* pB0 = Bt + (size_t)(n0 + lr) * IN_F + quad * 8;
    const unsigned short* pB1 = pB0 + 16 * IN_F;

    f32x4 acc0 = {0.f, 0.f, 0.f, 0.f};
    f32x4 acc1 = {0.f, 0.f, 0.f, 0.f};
    #pragma unroll 8
    for (int k0 = 0; k0 < IN_F; k0 += 32) {
        bf16x8 a  = *(const bf16x8*)(pA + k0);
        bf16x8 b0 = *(const bf16x8*)(pB0 + k0);
        bf16x8 b1 = *(const bf16x8*)(pB1 + k0);
        acc0 = __builtin_amdgcn_mfma_f32_16x16x32_bf16(a, b0, acc0, 0, 0, 0);
        acc1 = __builtin_amdgcn_mfma_f32_16x16x32_bf16(a, b1, acc1, 0, 0, 0);
    }
    // C/D: col = lane&15, row = quad*4 + r. Output Mt[o][b][k].
    float* base = Mt + (size_t)(n0 >> 5) * (BATCH * INTER) + (size_t)(m0 + quad * 4) * INTER;
    #pragma unroll
    for (int r = 0; r < 4; ++r) {
        base[r * INTER + lr]      = acc0[r];
        base[r * INTER + 16 + lr] = acc1[r];
    }
}

// ---------------- Pairwise L1 + exp: ma PINNED in VGPRs, mb via LDS broadcast ----------------
// grid (2 a-chunks, 64 o, 4 b-slices), block 256 (4 waves).
// asm volatile pins ma[4][32] (128 VGPRs): R5/R6 showed the allocator sinks the ma loads
// into the b-loop otherwise (VGPR_Count stayed 92), re-fetching ma every iteration (TA-bound).
__global__ __launch_bounds__(256, 2) void pairwise_kernel(const float* __restrict__ Mt,
                                                          float* __restrict__ out) {
    const int o    = blockIdx.y;
    const int ac   = blockIdx.x;         // 0..1
    const int bs   = blockIdx.z;         // 0..3
    const int tid  = threadIdx.x;
    const int lane = tid & 63;
    const int wave = tid >> 6;
    const float* slab = Mt + (size_t)o * (BATCH * INTER);

    __shared__ float mb_lds[128 * INTER];   // 16 KB: rows [bs*128, bs*128+128)
    {
        const float4* src = (const float4*)(slab + (size_t)bs * 128 * INTER);
        float4* dst = (float4*)mb_lds;
        #pragma unroll
        for (int i = 0; i < 4; ++i)
            dst[tid + 256 * i] = src[tid + 256 * i];
    }

    float ma[4][INTER];
    #pragma unroll
    for (int r = 0; r < 4; ++r) {
        const float* pa = slab + (size_t)(ac * 256 + r * 64 + lane) * INTER;
        #pragma unroll
        for (int k = 0; k < INTER; k += 4) {
            const float4 v = *(const float4*)(pa + k);
            ma[r][k] = v.x; ma[r][k + 1] = v.y; ma[r][k + 2] = v.z; ma[r][k + 3] = v.w;
        }
    }
    // Pin each element in a VGPR: volatile asm defines the value, so the loads above
    // cannot be sunk into / rematerialized inside the loop below.
    #pragma unroll
    for (int r = 0; r < 4; ++r)
        #pragma unroll
        for (int k = 0; k < INTER; ++k)
            asm volatile("" : "+v"(ma[r][k]));
    __syncthreads();

    float f[4] = {0.f, 0.f, 0.f, 0.f};
    const float* pb = mb_lds + wave * 32 * INTER;   // wave w covers 32 local b-rows
    #pragma unroll 2
    for (int b = 0; b < 32; ++b) {
        float d0[4] = {0.f, 0.f, 0.f, 0.f};
        float d1[4] = {0.f, 0.f, 0.f, 0.f};   // 8 independent accum chains
        #pragma unroll
        for (int k = 0; k < INTER; k += 4) {
            const float4 mb = *(const float4*)(pb + k);   // ds_read_b128, wave-uniform
            #pragma unroll
            for (int r = 0; r < 4; ++r) {
                d0[r] += fabsf(ma[r][k]     - mb.x);
                d1[r] += fabsf(ma[r][k + 1] - mb.y);
                d0[r] += fabsf(ma[r][k + 2] - mb.z);
                d1[r] += fabsf(ma[r][k + 3] - mb.w);
            }
        }
        #pragma unroll
        for (int r = 0; r < 4; ++r)
            f[r] += __expf(-(d0[r] + d1[r]));
        pb += INTER;
    }

    __shared__ float part[4][4][64];     // [wave][r][lane], 4 KB
    #pragma unroll
    for (int r = 0; r < 4; ++r)
        part[wave][r][lane] = f[r];
    __syncthreads();
    if (wave == 0) {
        #pragma unroll
        for (int r = 0; r < 4; ++r) {
            const float s = part[0][r][lane] + part[1][r][lane]
                          + part[2][r][lane] + part[3][r][lane];
            atomicAdd(&out[(size_t)(ac * 256 + r * 64 + lane) * OUT_W + IN_F + o], s);
        }
    }
}

extern "C" void kernel_launch(void* const* d_in, const int* in_sizes, int n_in,
                              void* d_out, int out_size, void* d_ws, size_t ws_size,
                              hipStream_t stream) {
    const float* x = (const float*)d_in[0];   // [512,1024] fp32
    const float* T = (const float*)d_in[1];   // [1024,2048] fp32 row-major (k-major)
    float* out = (float*)d_out;               // [512,1088] fp32

    // ws layout: xb (1MB) | Bt (4MB) | Mt (4MB) = 9MB
    unsigned short* xb = (unsigned short*)d_ws;                          // [512][1024] bf16
    unsigned short* Bt = (unsigned short*)((char*)d_ws + (1u << 20));    // [2048][1024] bf16
    float*          Mt = (float*)((char*)d_ws + (5u << 20));             // [64][512][32] fp32

    prep_kernel<<<1024, 256, 0, stream>>>(x, T, out, xb, Bt);

    dim3 ggrid(NCOL / 32, BATCH / 64);        // 64 x 8 = 512 blocks
    gemm_kernel<<<ggrid, 256, 0, stream>>>(xb, Bt, Mt);

    dim3 pgrid(2, OUT_F, 4);                  // 512 blocks, 2/CU
    pairwise_kernel<<<pgrid, 256, 0, stream>>>(Mt, out);
}

// Round 8
// 125.977 us; speedup vs baseline: 1.0285x; 1.0285x over previous
//
#include <hip/hip_runtime.h>
#include <hip/hip_bf16.h>

#define IN_F   1024
#define OUT_F  64
#define INTER  32
#define BATCH  512
#define NCOL   2048              // OUT_F * INTER
#define OUT_W  1088              // IN_F + OUT_F

typedef short bf16x8 __attribute__((ext_vector_type(8)));  // 8 bf16 (4 VGPRs)
typedef float f32x4  __attribute__((ext_vector_type(4)));  // 4 fp32 acc

__device__ __forceinline__ unsigned short f2bf(float v) {
    __hip_bfloat16 h = __float2bfloat16(v);
    return *reinterpret_cast<unsigned short*>(&h);
}

// ---------------- prep_x: copy x -> out, zero feature cols, cast x -> xb ----------------
__global__ __launch_bounds__(256) void prep_x_kernel(const float* __restrict__ x,
                                                     float* __restrict__ out,
                                                     unsigned short* __restrict__ xb) {
    const int tid = threadIdx.x;
    const int r = blockIdx.x;
    const float4 v = ((const float4*)(x + (size_t)r * IN_F))[tid];
    *(float4*)(out + (size_t)r * OUT_W + tid * 4) = v;
    unsigned short h[4] = {f2bf(v.x), f2bf(v.y), f2bf(v.z), f2bf(v.w)};
    *(uint2*)(xb + (size_t)r * IN_F + tid * 4) = *(uint2*)h;
    if (tid < OUT_F / 4)   // zero-init minibatch-feature cols (pairwise accumulates atomically)
        *(float4*)(out + (size_t)r * OUT_W + IN_F + tid * 4) = make_float4(0.f, 0.f, 0.f, 0.f);
}

// ---------------- transpose_T: T[k][n] fp32 -> Bt[n][k] bf16, 64x64 tiles ----------------
__global__ __launch_bounds__(256) void transpose_T_kernel(const float* __restrict__ T,
                                                          unsigned short* __restrict__ Bt) {
    __shared__ unsigned short ldsT[64][72];   // [n][k], row stride 144B (16B-aligned)
    const int tid = threadIdx.x;
    const int n0 = (blockIdx.x & 31) * 64;
    const int k0 = (blockIdx.x >> 5) * 64;
    const int nl = tid & 63;
    const int kc = (tid >> 6) * 16;
    unsigned short u[16];
    #pragma unroll
    for (int j = 0; j < 16; ++j)
        u[j] = f2bf(T[(size_t)(k0 + kc + j) * NCOL + n0 + nl]);
    *(uint4*)&ldsT[nl][kc]     = *(uint4*)&u[0];
    *(uint4*)&ldsT[nl][kc + 8] = *(uint4*)&u[8];
    __syncthreads();
    const int n2  = tid >> 2;
    const int kc2 = (tid & 3) * 16;
    uint4 a = *(uint4*)&ldsT[n2][kc2];
    uint4 b = *(uint4*)&ldsT[n2][kc2 + 8];
    unsigned short* dst = Bt + (size_t)(n0 + n2) * IN_F + k0 + kc2;
    *(uint4*)dst       = a;
    *(uint4*)(dst + 8) = b;
}

// ---------------- GEMM (bf16 MFMA, no LDS, no barriers) ----------------
__global__ __launch_bounds__(256) void gemm_kernel(const unsigned short* __restrict__ xb,
                                                   const unsigned short* __restrict__ Bt,
                                                   float* __restrict__ Mt) {
    const int tid  = threadIdx.x;
    const int wave = tid >> 6, lane = tid & 63;
    const int quad = lane >> 4, lr = lane & 15;
    const int m0 = (blockIdx.y * 4 + wave) * 16;
    const int n0 = blockIdx.x * 32;

    const unsigned short* pA  = xb + (size_t)(m0 + lr) * IN_F + quad * 8;
    const unsigned short* pB0 = Bt + (size_t)(n0 + lr) * IN_F + quad * 8;
    const unsigned short* pB1 = pB0 + 16 * IN_F;

    f32x4 acc0 = {0.f, 0.f, 0.f, 0.f};
    f32x4 acc1 = {0.f, 0.f, 0.f, 0.f};
    #pragma unroll 8
    for (int k0 = 0; k0 < IN_F; k0 += 32) {
        bf16x8 a  = *(const bf16x8*)(pA + k0);
        bf16x8 b0 = *(const bf16x8*)(pB0 + k0);
        bf16x8 b1 = *(const bf16x8*)(pB1 + k0);
        acc0 = __builtin_amdgcn_mfma_f32_16x16x32_bf16(a, b0, acc0, 0, 0, 0);
        acc1 = __builtin_amdgcn_mfma_f32_16x16x32_bf16(a, b1, acc1, 0, 0, 0);
    }
    // C/D: col = lane&15, row = quad*4 + r. Output Mt[o][b][k].
    float* base = Mt + (size_t)(n0 >> 5) * (BATCH * INTER) + (size_t)(m0 + quad * 4) * INTER;
    #pragma unroll
    for (int r = 0; r < 4; ++r) {
        base[r * INTER + lr]      = acc0[r];
        base[r * INTER + 16 + lr] = acc1[r];
    }
}

// ---------------- Pairwise: 2 a-rows/lane (64 VGPRs - no spill), mb via LDS broadcast ----------
// R7 post-mortem: ma[4][32]=128 floats spilled to AGPRs (VGPR_Count stuck at 92, ~128
// v_accvgpr_read per iter). 2 rows = 64 floats fits under the 128-VGPR cap of (256,4).
// grid (4 a-chunks, 64 o, 4 b-slices) = 1024 blocks = 4 blocks/CU = 16 waves/CU.
__global__ __launch_bounds__(256, 4) void pairwise_kernel(const float* __restrict__ Mt,
                                                          float* __restrict__ out) {
    const int o    = blockIdx.y;
    const int ac   = blockIdx.x;         // 0..3 -> 128 a-rows
    const int bs   = blockIdx.z;         // 0..3 -> 128 b-rows
    const int tid  = threadIdx.x;
    const int lane = tid & 63;
    const int wave = tid >> 6;
    const float* slab = Mt + (size_t)o * (BATCH * INTER);

    __shared__ float mb_lds[128 * INTER];   // 16 KB: rows [bs*128, bs*128+128)
    {
        const float4* src = (const float4*)(slab + (size_t)bs * 128 * INTER);
        float4* dst = (float4*)mb_lds;
        #pragma unroll
        for (int i = 0; i < 4; ++i)
            dst[tid + 256 * i] = src[tid + 256 * i];
    }

    float ma[2][INTER];                  // 64 VGPRs
    #pragma unroll
    for (int r = 0; r < 2; ++r) {
        const float* pa = slab + (size_t)(ac * 128 + r * 64 + lane) * INTER;
        #pragma unroll
        for (int k = 0; k < INTER; k += 4) {
            const float4 v = *(const float4*)(pa + k);
            ma[r][k] = v.x; ma[r][k + 1] = v.y; ma[r][k + 2] = v.z; ma[r][k + 3] = v.w;
        }
    }
    #pragma unroll
    for (int r = 0; r < 2; ++r)          // pin: loads may not be sunk into the loop
        #pragma unroll
        for (int k = 0; k < INTER; ++k)
            asm volatile("" : "+v"(ma[r][k]));
    __syncthreads();

    float f[2] = {0.f, 0.f};
    const float* pb = mb_lds + wave * 32 * INTER;   // wave w covers 32 local b-rows
    #pragma unroll 2
    for (int b = 0; b < 32; ++b) {
        float d0[2] = {0.f, 0.f};
        float d1[2] = {0.f, 0.f};        // 2 chains x 2 rows = 4 independent accums
        #pragma unroll
        for (int k = 0; k < INTER; k += 4) {
            const float4 mb = *(const float4*)(pb + k);   // ds_read_b128, wave-uniform broadcast
            #pragma unroll
            for (int r = 0; r < 2; ++r) {
                d0[r] += fabsf(ma[r][k]     - mb.x);
                d1[r] += fabsf(ma[r][k + 1] - mb.y);
                d0[r] += fabsf(ma[r][k + 2] - mb.z);
                d1[r] += fabsf(ma[r][k + 3] - mb.w);
            }
        }
        #pragma unroll
        for (int r = 0; r < 2; ++r)
            f[r] += __expf(-(d0[r] + d1[r]));
        pb += INTER;
    }

    __shared__ float part[4][2][64];     // [wave][r][lane], 2 KB
    #pragma unroll
    for (int r = 0; r < 2; ++r)
        part[wave][r][lane] = f[r];
    __syncthreads();
    if (wave == 0) {
        #pragma unroll
        for (int r = 0; r < 2; ++r) {
            const float s = part[0][r][lane] + part[1][r][lane]
                          + part[2][r][lane] + part[3][r][lane];
            atomicAdd(&out[(size_t)(ac * 128 + r * 64 + lane) * OUT_W + IN_F + o], s);
        }
    }
}

extern "C" void kernel_launch(void* const* d_in, const int* in_sizes, int n_in,
                              void* d_out, int out_size, void* d_ws, size_t ws_size,
                              hipStream_t stream) {
    const float* x = (const float*)d_in[0];   // [512,1024] fp32
    const float* T = (const float*)d_in[1];   // [1024,2048] fp32 row-major (k-major)
    float* out = (float*)d_out;               // [512,1088] fp32

    // ws layout: xb (1MB) | Bt (4MB) | Mt (4MB) = 9MB
    unsigned short* xb = (unsigned short*)d_ws;                          // [512][1024] bf16
    unsigned short* Bt = (unsigned short*)((char*)d_ws + (1u << 20));    // [2048][1024] bf16
    float*          Mt = (float*)((char*)d_ws + (5u << 20));             // [64][512][32] fp32

    prep_x_kernel<<<BATCH, 256, 0, stream>>>(x, out, xb);
    transpose_T_kernel<<<512, 256, 0, stream>>>(T, Bt);

    dim3 ggrid(NCOL / 32, BATCH / 64);        // 64 x 8 = 512 blocks
    gemm_kernel<<<ggrid, 256, 0, stream>>>(xb, Bt, Mt);

    dim3 pgrid(4, OUT_F, 4);                  // 1024 blocks, 4/CU
    pairwise_kernel<<<pgrid, 256, 0, stream>>>(Mt, out);
}

// Round 9
// 121.109 us; speedup vs baseline: 1.0698x; 1.0402x over previous
//
#include <hip/hip_runtime.h>
#include <hip/hip_bf16.h>

#define IN_F   1024
#define OUT_F  64
#define INTER  32
#define BATCH  512
#define NCOL   2048              // OUT_F * INTER
#define OUT_W  1088              // IN_F + OUT_F

typedef short bf16x8 __attribute__((ext_vector_type(8)));  // 8 bf16 (4 VGPRs)
typedef float f32x4  __attribute__((ext_vector_type(4)));  // 4 fp32 acc

__device__ __forceinline__ unsigned short f2bf(float v) {
    __hip_bfloat16 h = __float2bfloat16(v);
    return *reinterpret_cast<unsigned short*>(&h);
}

// ---------------- prep_x: copy x -> out, zero feature cols, cast x -> xb ----------------
__global__ __launch_bounds__(256) void prep_x_kernel(const float* __restrict__ x,
                                                     float* __restrict__ out,
                                                     unsigned short* __restrict__ xb) {
    const int tid = threadIdx.x;
    const int r = blockIdx.x;
    const float4 v = ((const float4*)(x + (size_t)r * IN_F))[tid];
    *(float4*)(out + (size_t)r * OUT_W + tid * 4) = v;
    unsigned short h[4] = {f2bf(v.x), f2bf(v.y), f2bf(v.z), f2bf(v.w)};
    *(uint2*)(xb + (size_t)r * IN_F + tid * 4) = *(uint2*)h;
    if (tid < OUT_F / 4)   // zero-init minibatch-feature cols (pairwise accumulates atomically)
        *(float4*)(out + (size_t)r * OUT_W + IN_F + tid * 4) = make_float4(0.f, 0.f, 0.f, 0.f);
}

// ---------------- transpose_T: T[k][n] fp32 -> Bt[n][k] bf16, 64x64 tiles ----------------
__global__ __launch_bounds__(256) void transpose_T_kernel(const float* __restrict__ T,
                                                          unsigned short* __restrict__ Bt) {
    __shared__ unsigned short ldsT[64][72];   // [n][k], row stride 144B (16B-aligned)
    const int tid = threadIdx.x;
    const int n0 = (blockIdx.x & 31) * 64;
    const int k0 = (blockIdx.x >> 5) * 64;
    const int nl = tid & 63;
    const int kc = (tid >> 6) * 16;
    unsigned short u[16];
    #pragma unroll
    for (int j = 0; j < 16; ++j)
        u[j] = f2bf(T[(size_t)(k0 + kc + j) * NCOL + n0 + nl]);
    *(uint4*)&ldsT[nl][kc]     = *(uint4*)&u[0];
    *(uint4*)&ldsT[nl][kc + 8] = *(uint4*)&u[8];
    __syncthreads();
    const int n2  = tid >> 2;
    const int kc2 = (tid & 3) * 16;
    uint4 a = *(uint4*)&ldsT[n2][kc2];
    uint4 b = *(uint4*)&ldsT[n2][kc2 + 8];
    unsigned short* dst = Bt + (size_t)(n0 + n2) * IN_F + k0 + kc2;
    *(uint4*)dst       = a;
    *(uint4*)(dst + 8) = b;
}

// ---------------- GEMM (bf16 MFMA, no LDS, no barriers) ----------------
__global__ __launch_bounds__(256) void gemm_kernel(const unsigned short* __restrict__ xb,
                                                   const unsigned short* __restrict__ Bt,
                                                   float* __restrict__ Mt) {
    const int tid  = threadIdx.x;
    const int wave = tid >> 6, lane = tid & 63;
    const int quad = lane >> 4, lr = lane & 15;
    const int m0 = (blockIdx.y * 4 + wave) * 16;
    const int n0 = blockIdx.x * 32;

    const unsigned short* pA  = xb + (size_t)(m0 + lr) * IN_F + quad * 8;
    const unsigned short* pB0 = Bt + (size_t)(n0 + lr) * IN_F + quad * 8;
    const unsigned short* pB1 = pB0 + 16 * IN_F;

    f32x4 acc0 = {0.f, 0.f, 0.f, 0.f};
    f32x4 acc1 = {0.f, 0.f, 0.f, 0.f};
    #pragma unroll 8
    for (int k0 = 0; k0 < IN_F; k0 += 32) {
        bf16x8 a  = *(const bf16x8*)(pA + k0);
        bf16x8 b0 = *(const bf16x8*)(pB0 + k0);
        bf16x8 b1 = *(const bf16x8*)(pB1 + k0);
        acc0 = __builtin_amdgcn_mfma_f32_16x16x32_bf16(a, b0, acc0, 0, 0, 0);
        acc1 = __builtin_amdgcn_mfma_f32_16x16x32_bf16(a, b1, acc1, 0, 0, 0);
    }
    // C/D: col = lane&15, row = quad*4 + r. Output Mt[o][b][k].
    float* base = Mt + (size_t)(n0 >> 5) * (BATCH * INTER) + (size_t)(m0 + quad * 4) * INTER;
    #pragma unroll
    for (int r = 0; r < 4; ++r) {
        base[r * INTER + lr]      = acc0[r];
        base[r * INTER + 16 + lr] = acc1[r];
    }
}

// ---------------- Pairwise: 1 a-row/lane (32 VGPRs, huge headroom), mb via LDS broadcast ----
// R8 post-mortem: even ma[2][32]=64 floats got evicted (VGPR=52). Rule learned: the array
// must sit well UNDER half the cap. ma[32]=32 floats under a 64-VGPR cap (256,8) leaves
// ~50% headroom for scheduler pressure spikes. grid (8 ac, 64 o, 8 bs) = 4096 blocks
// = 8 blocks/CU = 32 waves/CU (full occupancy). Wave w covers 16 of the block's 64 b-rows.
__global__ __launch_bounds__(256, 8) void pairwise_kernel(const float* __restrict__ Mt,
                                                          float* __restrict__ out) {
    const int o    = blockIdx.y;
    const int ac   = blockIdx.x;         // 0..7 -> 64 a-rows
    const int bs   = blockIdx.z;         // 0..7 -> 64 b-rows
    const int tid  = threadIdx.x;
    const int lane = tid & 63;
    const int wave = tid >> 6;
    const float* slab = Mt + (size_t)o * (BATCH * INTER);

    __shared__ float mb_lds[64 * INTER];    // 8 KB: rows [bs*64, bs*64+64)
    {
        const float4* src = (const float4*)(slab + (size_t)bs * 64 * INTER);
        float4* dst = (float4*)mb_lds;
        dst[tid]       = src[tid];
        dst[tid + 256] = src[tid + 256];
    }

    float ma[INTER];                     // 32 VGPRs
    {
        const float* pa = slab + (size_t)(ac * 64 + lane) * INTER;
        #pragma unroll
        for (int k = 0; k < INTER; k += 4) {
            const float4 v = *(const float4*)(pa + k);
            ma[k] = v.x; ma[k + 1] = v.y; ma[k + 2] = v.z; ma[k + 3] = v.w;
        }
    }
    #pragma unroll
    for (int k = 0; k < INTER; ++k)      // pin: loads may not be re-issued inside the loop
        asm volatile("" : "+v"(ma[k]));
    __syncthreads();

    float f = 0.f;
    const float* pb = mb_lds + wave * 16 * INTER;   // wave w covers 16 local b-rows
    for (int b = 0; b < 16; ++b) {
        float d0 = 0.f, d1 = 0.f, d2 = 0.f, d3 = 0.f;   // 4 independent chains
        #pragma unroll
        for (int k = 0; k < INTER; k += 4) {
            const float4 mb = *(const float4*)(pb + k);  // ds_read_b128, wave-uniform broadcast
            d0 += fabsf(ma[k]     - mb.x);
            d1 += fabsf(ma[k + 1] - mb.y);
            d2 += fabsf(ma[k + 2] - mb.z);
            d3 += fabsf(ma[k + 3] - mb.w);
        }
        f += __expf(-((d0 + d1) + (d2 + d3)));
        pb += INTER;
    }

    __shared__ float part[4][64];        // 1 KB
    part[wave][lane] = f;
    __syncthreads();
    if (wave == 0) {
        const float s = part[0][lane] + part[1][lane] + part[2][lane] + part[3][lane];
        atomicAdd(&out[(size_t)(ac * 64 + lane) * OUT_W + IN_F + o], s);
    }
}

extern "C" void kernel_launch(void* const* d_in, const int* in_sizes, int n_in,
                              void* d_out, int out_size, void* d_ws, size_t ws_size,
                              hipStream_t stream) {
    const float* x = (const float*)d_in[0];   // [512,1024] fp32
    const float* T = (const float*)d_in[1];   // [1024,2048] fp32 row-major (k-major)
    float* out = (float*)d_out;               // [512,1088] fp32

    // ws layout: xb (1MB) | Bt (4MB) | Mt (4MB) = 9MB
    unsigned short* xb = (unsigned short*)d_ws;                          // [512][1024] bf16
    unsigned short* Bt = (unsigned short*)((char*)d_ws + (1u << 20));    // [2048][1024] bf16
    float*          Mt = (float*)((char*)d_ws + (5u << 20));             // [64][512][32] fp32

    prep_x_kernel<<<BATCH, 256, 0, stream>>>(x, out, xb);
    transpose_T_kernel<<<512, 256, 0, stream>>>(T, Bt);

    dim3 ggrid(NCOL / 32, BATCH / 64);        // 64 x 8 = 512 blocks
    gemm_kernel<<<ggrid, 256, 0, stream>>>(xb, Bt, Mt);

    dim3 pgrid(8, OUT_F, 8);                  // 4096 blocks, 8/CU
    pairwise_kernel<<<pgrid, 256, 0, stream>>>(Mt, out);
}